// Round 4
// baseline (164.814 us; speedup 1.0000x reference)
//
#include <hip/hip_runtime.h>
#include <hip/hip_bf16.h>

#define TD_B 512

typedef __bf16 bf16x8 __attribute__((ext_vector_type(8)));
typedef __bf16 bf16x4 __attribute__((ext_vector_type(4)));
typedef float  f32x4  __attribute__((ext_vector_type(4)));

#define MFMA(a, b, c) __builtin_amdgcn_mfma_f32_16x16x32_bf16((a), (b), (c), 0, 0, 0)

__device__ __forceinline__ float sigf(float x)  { return 1.0f / (1.0f + __expf(-x)); }
__device__ __forceinline__ float tanhf_(float x){ return 2.0f / (1.0f + __expf(-2.0f * x)) - 1.0f; }

extern "C" __global__ void __launch_bounds__(64, 1)
traj_disc_kernel(const float* __restrict__ x, const float* __restrict__ dmat,
                 const float* __restrict__ bmat, const float* __restrict__ hmat,
                 const float* __restrict__ mask,
                 const float* __restrict__ emb_w, const float* __restrict__ emb_b,
                 const float* __restrict__ w_ih, const float* __restrict__ w_hh,
                 const float* __restrict__ b_ih, const float* __restrict__ b_hh,
                 const float* __restrict__ e2a_w, const float* __restrict__ e2a_b,
                 const float* __restrict__ dom,
                 const float* __restrict__ sp_w, const float* __restrict__ sp_b,
                 const float* __restrict__ a2e_w, const float* __restrict__ a2e_b,
                 const float* __restrict__ w1, const float* __restrict__ b1,
                 const float* __restrict__ w2, const float* __restrict__ b2,
                 const float* __restrict__ w3, const float* __restrict__ b3,
                 float* __restrict__ out)
{
    const int b    = blockIdx.x;
    const int lane = threadIdx.x;
    const int l15  = lane & 15;
    const int lg   = lane >> 4;      // 0..3

    // one batch per wave; all buffers wave-private; NO __syncthreads in the loop
    __shared__ __bf16 sAin[32][72];   // 0-15 xe | 16-47 h | 48 ones | 49-63 zero
    __shared__ __bf16 sHl [32][40];
    __shared__ __bf16 sWN [32][40];
    __shared__ __bf16 sHaT[32][40];
    __shared__ __bf16 sEmb[32][40];
    __shared__ __bf16 sPA [32][72];   // 0-31 ha | 32-63 att
    __shared__ float  sMaskT[20][36];
    __shared__ float  sDom[144];
    __shared__ float  sEmbW[3][16];   // rows 0,1 emb_w; row 2 emb_b
    __shared__ __bf16 z1bf[32][136];
    __shared__ __bf16 z2bf[32][136];

    // ---- staging (in-wave, compiler-ordered) ----
    for (int idx = lane; idx < 32 * 72; idx += 64) (&sAin[0][0])[idx] = (__bf16)0.0f;
    for (int idx = lane; idx < 640; idx += 64) {
        int tt = idx >> 5, n = idx & 31;
        sMaskT[tt][n] = mask[(b * 32 + n) * 20 + tt];
    }
    for (int idx = lane; idx < 144; idx += 64) sDom[idx] = dom[idx];
    if (lane < 32) sEmbW[lane >> 4][lane & 15] = emb_w[lane];
    if (lane >= 32 && lane < 48) sEmbW[2][lane - 32] = emb_b[lane - 32];
    if (lane < 32) sAin[lane][48] = (__bf16)1.0f;   // ones column (gate bias)

    // ---- persistent register fragments ----
    // gates^T: A = [W_ih;W_hh;bias]^T, plain col order c = g*32+h
    bf16x8 Ag[8][2];
    #pragma unroll
    for (int mt = 0; mt < 8; ++mt)
        #pragma unroll
        for (int kt = 0; kt < 2; ++kt)
            #pragma unroll
            for (int j = 0; j < 8; ++j) {
                int k = kt * 32 + lg * 8 + j, c = mt * 16 + l15;
                float v;
                if (k < 16)      v = w_ih[k * 128 + c];
                else if (k < 48) v = w_hh[(k - 16) * 128 + c];
                else if (k == 48) v = b_ih[c] + b_hh[c];
                else             v = 0.0f;
                Ag[mt][kt][j] = (__bf16)v;
            }
    bf16x8 Be2a[2], Ba2e[2], Bsp[2][2];
    #pragma unroll
    for (int nt = 0; nt < 2; ++nt) {
        int c = nt * 16 + l15;
        #pragma unroll
        for (int j = 0; j < 8; ++j) {
            Be2a[nt][j] = (__bf16)e2a_w[(lg * 8 + j) * 32 + c];
            Ba2e[nt][j] = (__bf16)a2e_w[(lg * 8 + j) * 32 + c];
        }
        #pragma unroll
        for (int kt = 0; kt < 2; ++kt)
            #pragma unroll
            for (int j = 0; j < 8; ++j)
                Bsp[kt][nt][j] = (__bf16)sp_w[(kt * 32 + lg * 8 + j) * 32 + c];
    }
    const float bE[2] = { e2a_b[l15], e2a_b[16 + l15] };
    const float bS[2] = { sp_b[l15],  sp_b[16 + l15] };
    const float bA[2] = { a2e_b[l15], a2e_b[16 + l15] };

    float cst[2][2][4];                 // [nt][hb][q], cell state in registers
    #pragma unroll
    for (int a = 0; a < 2; ++a)
        #pragma unroll
        for (int bq = 0; bq < 2; ++bq)
            #pragma unroll
            for (int q = 0; q < 4; ++q) cst[a][bq][q] = 0.0f;
    f32x4 accZ[2][8] = {};              // online z1
    bf16x8 Bw1cur[8];

    // prefetch t=0 inputs (lane -> row i = lane>>1, half ch = lane&1)
    const int i0 = lane >> 1, ch = lane & 1;
    float4 pdv[4], pbv[4], phv[4]; float px;
    {
        int base = ((b * 32 + i0) * 20 + 0) * 32 + ch * 16;
        #pragma unroll
        for (int q = 0; q < 4; ++q) {
            pdv[q] = *(const float4*)(dmat + base + 4 * q);
            pbv[q] = *(const float4*)(bmat + base + 4 * q);
            phv[q] = *(const float4*)(hmat + base + 4 * q);
        }
        px = x[((b * 32 + i0) * 20 + 0) * 2 + ch];
    }

    #pragma unroll 1
    for (int t = 0; t < 20; ++t) {
        // ---- z1 accumulate for h_{t-1} (sAin h-cols still hold it) ----
        if (t >= 1) {
            bf16x8 az[2];
            #pragma unroll
            for (int mt = 0; mt < 2; ++mt)
                az[mt] = *(const bf16x8*)&sAin[mt * 16 + l15][16 + lg * 8];
            #pragma unroll
            for (int mt = 0; mt < 2; ++mt)
                #pragma unroll
                for (int nt = 0; nt < 8; ++nt)
                    accZ[mt][nt] = MFMA(az[mt], Bw1cur[nt], accZ[mt][nt]);
        }
        // stream w1 rows t*32.. (consumed next step / tail)
        #pragma unroll
        for (int nt = 0; nt < 8; ++nt)
            #pragma unroll
            for (int j = 0; j < 8; ++j)
                Bw1cur[nt][j] = (__bf16)w1[(t * 32 + lg * 8 + j) * 128 + nt * 16 + l15];

        // ---- wmat + normalize (registers) + xe ----
        {
            float mi = sMaskT[t][i0];
            float wq[4][4], ssum = 0.0f;
            #pragma unroll
            for (int q = 0; q < 4; ++q) {
                float4 mjv = *(const float4*)&sMaskT[t][ch * 16 + 4 * q];
                #pragma unroll
                for (int e = 0; e < 4; ++e) {
                    float bq = (&pbv[q].x)[e], hq = (&phv[q].x)[e];
                    int ib = (int)floorf(bq * (1.0f / 30.0f)); ib = ib < 0 ? 0 : (ib > 11 ? 11 : ib);
                    int ih = (int)floorf(hq * (1.0f / 30.0f)); ih = ih < 0 ? 0 : (ih > 11 ? 11 : ih);
                    float v = sDom[ib * 12 + ih] - (&pdv[q].x)[e];
                    v = v > 0.0f ? v : 0.0f;
                    v *= (&mjv.x)[e];
                    wq[q][e] = v;
                    ssum += v;
                }
            }
            ssum += __shfl_xor(ssum, 1);
            float inv = mi / (mi * ssum + 1e-8f);
            #pragma unroll
            for (int q = 0; q < 4; ++q) {
                bf16x4 wn4;
                #pragma unroll
                for (int e = 0; e < 4; ++e) wn4[e] = (__bf16)(wq[q][e] * inv);
                *(bf16x4*)&sWN[i0][ch * 16 + 4 * q] = wn4;
            }
            // xe: lane covers row i0, e-half ch*8
            float other = __shfl_xor(px, 1);
            float x0v = ch ? other : px;
            float x1v = ch ? px : other;
            int eh = ch * 8;
            float4 wa0 = *(const float4*)&sEmbW[0][eh], wa1 = *(const float4*)&sEmbW[0][eh + 4];
            float4 wb0 = *(const float4*)&sEmbW[1][eh], wb1 = *(const float4*)&sEmbW[1][eh + 4];
            float4 be0 = *(const float4*)&sEmbW[2][eh], be1 = *(const float4*)&sEmbW[2][eh + 4];
            bf16x4 xv0, xv1;
            #pragma unroll
            for (int q = 0; q < 4; ++q) {
                xv0[q] = (__bf16)(x0v * (&wa0.x)[q] + x1v * (&wb0.x)[q] + (&be0.x)[q]);
                xv1[q] = (__bf16)(x0v * (&wa1.x)[q] + x1v * (&wb1.x)[q] + (&be1.x)[q]);
            }
            *(bf16x4*)&sAin[i0][eh]     = xv0;
            *(bf16x4*)&sAin[i0][eh + 4] = xv1;
        }
        // prefetch t+1
        if (t < 19) {
            int base = ((b * 32 + i0) * 20 + (t + 1)) * 32 + ch * 16;
            #pragma unroll
            for (int q = 0; q < 4; ++q) {
                pdv[q] = *(const float4*)(dmat + base + 4 * q);
                pbv[q] = *(const float4*)(bmat + base + 4 * q);
                phv[q] = *(const float4*)(hmat + base + 4 * q);
            }
            px = x[((b * 32 + i0) * 20 + (t + 1)) * 2 + ch];
        }

        // ---- gates^T = Ag @ xh^T : C[c][n], all 4 gates lane-local ----
        bf16x8 bxh[2][2];
        #pragma unroll
        for (int nt = 0; nt < 2; ++nt)
            #pragma unroll
            for (int kt = 0; kt < 2; ++kt)
                bxh[nt][kt] = *(const bf16x8*)&sAin[nt * 16 + l15][kt * 32 + lg * 8];
        f32x4 cg[8][2];
        #pragma unroll
        for (int mt = 0; mt < 8; ++mt)
            #pragma unroll
            for (int nt = 0; nt < 2; ++nt) {
                f32x4 cc = {0.f, 0.f, 0.f, 0.f};
                cc = MFMA(Ag[mt][0], bxh[nt][0], cc);
                cc = MFMA(Ag[mt][1], bxh[nt][1], cc);
                cg[mt][nt] = cc;
            }

        // ---- LSTM cell: fully lane-local; n = nt*16+l15, h = hb*16+4lg+q ----
        #pragma unroll
        for (int nt = 0; nt < 2; ++nt)
            #pragma unroll
            for (int hb = 0; hb < 2; ++hb) {
                bf16x4 hlv;
                #pragma unroll
                for (int q = 0; q < 4; ++q) {
                    float gi = cg[0 + hb][nt][q];
                    float gf = cg[2 + hb][nt][q];
                    float gg = cg[4 + hb][nt][q];
                    float go = cg[6 + hb][nt][q];
                    float cn = sigf(gf) * cst[nt][hb][q] + sigf(gi) * tanhf_(gg);
                    cst[nt][hb][q] = cn;
                    hlv[q] = (__bf16)(sigf(go) * tanhf_(cn));
                }
                *(bf16x4*)&sHl[nt * 16 + l15][hb * 16 + 4 * lg] = hlv;
            }

        // ---- ha = hl @ e2a + b ----
        bf16x8 ahl[2];
        #pragma unroll
        for (int mt = 0; mt < 2; ++mt)
            ahl[mt] = *(const bf16x8*)&sHl[mt * 16 + l15][lg * 8];
        #pragma unroll
        for (int mt = 0; mt < 2; ++mt)
            #pragma unroll
            for (int nt = 0; nt < 2; ++nt) {
                f32x4 cc = {0.f, 0.f, 0.f, 0.f};
                cc = MFMA(ahl[mt], Be2a[nt], cc);
                bf16x4 tv;
                #pragma unroll
                for (int q = 0; q < 4; ++q) {
                    float v = cc[q] + bE[nt];
                    tv[q] = (__bf16)v;
                    sPA[mt * 16 + 4 * lg + q][nt * 16 + l15] = (__bf16)v;
                }
                *(bf16x4*)&sHaT[nt * 16 + l15][mt * 16 + 4 * lg] = tv;
            }

        // ---- att = wN @ ha ----
        bf16x8 awn[2], bht[2];
        #pragma unroll
        for (int mt = 0; mt < 2; ++mt) {
            awn[mt] = *(const bf16x8*)&sWN [mt * 16 + l15][lg * 8];
            bht[mt] = *(const bf16x8*)&sHaT[mt * 16 + l15][lg * 8];
        }
        #pragma unroll
        for (int mt = 0; mt < 2; ++mt)
            #pragma unroll
            for (int nt = 0; nt < 2; ++nt) {
                f32x4 cc = {0.f, 0.f, 0.f, 0.f};
                cc = MFMA(awn[mt], bht[nt], cc);
                #pragma unroll
                for (int q = 0; q < 4; ++q)
                    sPA[mt * 16 + 4 * lg + q][32 + nt * 16 + l15] = (__bf16)cc[q];
            }

        // ---- emb = tanh([ha|att] @ sp + b) ----
        bf16x8 apa[2][2];
        #pragma unroll
        for (int mt = 0; mt < 2; ++mt)
            #pragma unroll
            for (int kt = 0; kt < 2; ++kt)
                apa[mt][kt] = *(const bf16x8*)&sPA[mt * 16 + l15][kt * 32 + lg * 8];
        #pragma unroll
        for (int mt = 0; mt < 2; ++mt)
            #pragma unroll
            for (int nt = 0; nt < 2; ++nt) {
                f32x4 cc = {0.f, 0.f, 0.f, 0.f};
                cc = MFMA(apa[mt][0], Bsp[0][nt], cc);
                cc = MFMA(apa[mt][1], Bsp[1][nt], cc);
                #pragma unroll
                for (int q = 0; q < 4; ++q)
                    sEmb[mt * 16 + 4 * lg + q][nt * 16 + l15] = (__bf16)tanhf_(cc[q] + bS[nt]);
            }

        // ---- h_new = emb @ a2e + b -> sAin cols 16-47 ----
        bf16x8 aem[2];
        #pragma unroll
        for (int mt = 0; mt < 2; ++mt)
            aem[mt] = *(const bf16x8*)&sEmb[mt * 16 + l15][lg * 8];
        #pragma unroll
        for (int mt = 0; mt < 2; ++mt)
            #pragma unroll
            for (int nt = 0; nt < 2; ++nt) {
                f32x4 cc = {0.f, 0.f, 0.f, 0.f};
                cc = MFMA(aem[mt], Ba2e[nt], cc);
                #pragma unroll
                for (int q = 0; q < 4; ++q)
                    sAin[mt * 16 + 4 * lg + q][16 + nt * 16 + l15] = (__bf16)(cc[q] + bA[nt]);
            }
    }

    // ================= tail =================
    // final z1 accumulate (h_19 with w1 rows 608-639)
    {
        bf16x8 az[2];
        #pragma unroll
        for (int mt = 0; mt < 2; ++mt)
            az[mt] = *(const bf16x8*)&sAin[mt * 16 + l15][16 + lg * 8];
        #pragma unroll
        for (int mt = 0; mt < 2; ++mt)
            #pragma unroll
            for (int nt = 0; nt < 8; ++nt)
                accZ[mt][nt] = MFMA(az[mt], Bw1cur[nt], accZ[mt][nt]);
    }
    // z1 = leaky(accZ + b1)
    #pragma unroll
    for (int mt = 0; mt < 2; ++mt)
        #pragma unroll
        for (int nt = 0; nt < 8; ++nt) {
            float bias = b1[nt * 16 + l15];
            #pragma unroll
            for (int q = 0; q < 4; ++q) {
                float v = accZ[mt][nt][q] + bias;
                v = v > 0.f ? v : 0.2f * v;
                z1bf[mt * 16 + 4 * lg + q][nt * 16 + l15] = (__bf16)v;
            }
        }
    // z2 = leaky(z1 @ w2 + b2)
    {
        bf16x8 a2[2][4];
        #pragma unroll
        for (int mt = 0; mt < 2; ++mt)
            #pragma unroll
            for (int kt = 0; kt < 4; ++kt)
                a2[mt][kt] = *(const bf16x8*)&z1bf[mt * 16 + l15][kt * 32 + lg * 8];
        #pragma unroll
        for (int nt = 0; nt < 8; ++nt) {
            bf16x8 bw2k[4];
            #pragma unroll
            for (int kt = 0; kt < 4; ++kt)
                #pragma unroll
                for (int j = 0; j < 8; ++j)
                    bw2k[kt][j] = (__bf16)w2[(kt * 32 + lg * 8 + j) * 128 + nt * 16 + l15];
            float bias = b2[nt * 16 + l15];
            #pragma unroll
            for (int mt = 0; mt < 2; ++mt) {
                f32x4 cc = {0.f, 0.f, 0.f, 0.f};
                #pragma unroll
                for (int kt = 0; kt < 4; ++kt)
                    cc = MFMA(a2[mt][kt], bw2k[kt], cc);
                #pragma unroll
                for (int q = 0; q < 4; ++q) {
                    float v = cc[q] + bias;
                    v = v > 0.f ? v : 0.2f * v;
                    z2bf[mt * 16 + 4 * lg + q][nt * 16 + l15] = (__bf16)v;
                }
            }
        }
    }
    // z3 = sigmoid(z2 @ w3 + b3)
    {
        int n = lane >> 1, kh = (lane & 1) * 64;
        float s = 0.0f;
        #pragma unroll
        for (int p = 0; p < 8; ++p) {
            bf16x8 v = *(const bf16x8*)&z2bf[n][kh + p * 8];
            #pragma unroll
            for (int j = 0; j < 8; ++j)
                s += (float)v[j] * w3[kh + p * 8 + j];
        }
        s += __shfl_xor(s, 1);
        if ((lane & 1) == 0) out[b * 32 + n] = sigf(s + b3[0]);
    }
}

extern "C" void kernel_launch(void* const* d_in, const int* in_sizes, int n_in,
                              void* d_out, int out_size, void* d_ws, size_t ws_size,
                              hipStream_t stream) {
    (void)in_sizes; (void)n_in; (void)d_ws; (void)ws_size; (void)out_size;
    const float* x     = (const float*)d_in[0];
    const float* dmat  = (const float*)d_in[1];
    const float* bmat  = (const float*)d_in[2];
    const float* hmat  = (const float*)d_in[3];
    const float* mask  = (const float*)d_in[4];
    const float* emb_w = (const float*)d_in[5];
    const float* emb_b = (const float*)d_in[6];
    const float* w_ih  = (const float*)d_in[7];
    const float* w_hh  = (const float*)d_in[8];
    const float* b_ih  = (const float*)d_in[9];
    const float* b_hh  = (const float*)d_in[10];
    const float* e2a_w = (const float*)d_in[11];
    const float* e2a_b = (const float*)d_in[12];
    const float* dom   = (const float*)d_in[13];
    const float* sp_w  = (const float*)d_in[14];
    const float* sp_b  = (const float*)d_in[15];
    const float* a2e_w = (const float*)d_in[16];
    const float* a2e_b = (const float*)d_in[17];
    const float* w1    = (const float*)d_in[18];
    const float* b1    = (const float*)d_in[19];
    const float* w2    = (const float*)d_in[20];
    const float* b2    = (const float*)d_in[21];
    const float* w3    = (const float*)d_in[22];
    const float* b3    = (const float*)d_in[23];
    float* out = (float*)d_out;

    traj_disc_kernel<<<dim3(TD_B), dim3(64), 0, stream>>>(
        x, dmat, bmat, hmat, mask, emb_w, emb_b, w_ih, w_hh, b_ih, b_hh,
        e2a_w, e2a_b, dom, sp_w, sp_b, a2e_w, a2e_b,
        w1, b1, w2, b2, w3, b3, out);
}

// Round 5
// 72.708 us; speedup vs baseline: 2.2668x; 2.2668x over previous
//
#include <hip/hip_runtime.h>
#include <hip/hip_bf16.h>

#define TD_B 512

typedef __bf16 bf16x8 __attribute__((ext_vector_type(8)));
typedef __bf16 bf16x4 __attribute__((ext_vector_type(4)));
typedef float  f32x4  __attribute__((ext_vector_type(4)));

#define MFMA(a, b, c) __builtin_amdgcn_mfma_f32_16x16x32_bf16((a), (b), (c), 0, 0, 0)

__device__ __forceinline__ float sigf(float x)  { return 1.0f / (1.0f + __expf(-x)); }
__device__ __forceinline__ float tanhf_(float x){ return 2.0f / (1.0f + __expf(-2.0f * x)) - 1.0f; }

extern "C" __global__ void __launch_bounds__(256, 2)
traj_disc_kernel(const float* __restrict__ x, const float* __restrict__ dmat,
                 const float* __restrict__ bmat, const float* __restrict__ hmat,
                 const float* __restrict__ mask,
                 const float* __restrict__ emb_w, const float* __restrict__ emb_b,
                 const float* __restrict__ w_ih, const float* __restrict__ w_hh,
                 const float* __restrict__ b_ih, const float* __restrict__ b_hh,
                 const float* __restrict__ e2a_w, const float* __restrict__ e2a_b,
                 const float* __restrict__ dom,
                 const float* __restrict__ sp_w, const float* __restrict__ sp_b,
                 const float* __restrict__ a2e_w, const float* __restrict__ a2e_b,
                 const float* __restrict__ w1, const float* __restrict__ b1,
                 const float* __restrict__ w2, const float* __restrict__ b2,
                 const float* __restrict__ w3, const float* __restrict__ b3,
                 float* __restrict__ out)
{
    const int b    = blockIdx.x;
    const int tid  = threadIdx.x;
    const int lane = tid & 63;
    const int w    = tid >> 6;       // wave 0..3
    const int l15  = lane & 15;
    const int lg   = lane >> 4;      // 0..3

    __shared__ __bf16 sAin[32][72];   // 0-15 xe | 16-47 h | 48 ones | 49-63 zero
    __shared__ __bf16 sHl [32][40];
    __shared__ __bf16 sWN [32][40];
    __shared__ __bf16 sHaT[32][40];
    __shared__ __bf16 sEmb[32][40];
    __shared__ __bf16 sPA [32][72];   // 0-31 ha | 32-63 att
    __shared__ float  sMaskT[20][36];
    __shared__ float  sDom[144];
    __shared__ __bf16 z1bf[32][136];
    __shared__ __bf16 z2bf[32][136];

    // ---- staging ----
    for (int idx = tid; idx < 32 * 72; idx += 256)
        (&sAin[0][0])[idx] = (idx % 72 == 48) ? (__bf16)1.0f : (__bf16)0.0f;
    for (int idx = tid; idx < 640; idx += 256) {
        int tt = idx >> 5, n = idx & 31;
        sMaskT[tt][n] = mask[(b * 32 + n) * 20 + tt];
    }
    if (tid < 144) sDom[tid] = dom[tid];

    // per-thread hoisted constants (phase-A mapping: row i0, quad p0)
    const int i0 = tid >> 3, p0 = tid & 7;
    const float ewa0 = emb_w[2 * p0],      ewa1 = emb_w[2 * p0 + 1];
    const float ewb0 = emb_w[16 + 2 * p0], ewb1 = emb_w[16 + 2 * p0 + 1];
    const float eb0  = emb_b[2 * p0],      eb1  = emb_b[2 * p0 + 1];

    // ---- transposed-gates A-fragments (gate-interleaved cols c=4h+g) ----
    // Ag[mtl][kt][j] = W'[kt*32+lg*8+j][src_col(c)], c = (2w+mtl)*16 + l15
    bf16x8 Ag[2][2];
    #pragma unroll
    for (int mtl = 0; mtl < 2; ++mtl) {
        int c  = (2 * w + mtl) * 16 + l15;
        int cg = (c & 3) * 32 + (c >> 2);     // source col g*32+h
        #pragma unroll
        for (int kt = 0; kt < 2; ++kt)
            #pragma unroll
            for (int j = 0; j < 8; ++j) {
                int k = kt * 32 + lg * 8 + j;
                float v;
                if (k < 16)       v = w_ih[k * 128 + cg];
                else if (k < 48)  v = w_hh[(k - 16) * 128 + cg];
                else if (k == 48) v = b_ih[cg] + b_hh[cg];
                else              v = 0.0f;
                Ag[mtl][kt][j] = (__bf16)v;
            }
    }
    // per-wave output tile for 2x2-split phases C-F
    const int mtw = w >> 1, ntw = w & 1;
    const int cw  = ntw * 16 + l15;
    bf16x8 Be2a, Ba2e, Bsp[2];
    #pragma unroll
    for (int j = 0; j < 8; ++j) {
        Be2a[j] = (__bf16)e2a_w[(lg * 8 + j) * 32 + cw];
        Ba2e[j] = (__bf16)a2e_w[(lg * 8 + j) * 32 + cw];
    }
    #pragma unroll
    for (int kt = 0; kt < 2; ++kt)
        #pragma unroll
        for (int j = 0; j < 8; ++j)
            Bsp[kt][j] = (__bf16)sp_w[(kt * 32 + lg * 8 + j) * 32 + cw];
    const float bEw = e2a_b[cw], bSw = sp_b[cw], bAw = a2e_b[cw];

    float cst[2][2] = {{0.f, 0.f}, {0.f, 0.f}};  // cell state [mtl][nt], lane-local
    f32x4 accZ[2][2] = {};                       // online z1 [mt][ntp]
    bf16x8 Bw1cur[2];

    // prefetch t=0 inputs
    float4 pdv, pbv, phv; float px0, px1;
    {
        int base = ((b * 32 + i0) * 20 + 0) * 32 + 4 * p0;
        pdv = *(const float4*)(dmat + base);
        pbv = *(const float4*)(bmat + base);
        phv = *(const float4*)(hmat + base);
        int xb = ((b * 32 + i0) * 20 + 0) * 2;
        px0 = x[xb]; px1 = x[xb + 1];
    }
    __syncthreads();

    #pragma unroll 1
    for (int t = 0; t < 20; ++t) {
        // ===== phase A: wmat+normalize (regs), wN store, xe store; prefetch t+1 =====
        {
            float4 dv = pdv, bv = pbv, hv = phv;
            float xx0 = px0, xx1 = px1;
            if (t < 19) {
                int base = ((b * 32 + i0) * 20 + (t + 1)) * 32 + 4 * p0;
                pdv = *(const float4*)(dmat + base);
                pbv = *(const float4*)(bmat + base);
                phv = *(const float4*)(hmat + base);
                int xb = ((b * 32 + i0) * 20 + (t + 1)) * 2;
                px0 = x[xb]; px1 = x[xb + 1];
            }
            float4 mj = *(const float4*)&sMaskT[t][4 * p0];
            float  mi = sMaskT[t][i0];
            float wq[4];
            #pragma unroll
            for (int q = 0; q < 4; ++q) {
                float bq = (&bv.x)[q], hq = (&hv.x)[q];
                int ib = (int)floorf(bq * (1.0f / 30.0f)); ib = ib < 0 ? 0 : (ib > 11 ? 11 : ib);
                int ih = (int)floorf(hq * (1.0f / 30.0f)); ih = ih < 0 ? 0 : (ih > 11 ? 11 : ih);
                float v = sDom[ib * 12 + ih] - (&dv.x)[q];
                v = v > 0.f ? v : 0.f;
                wq[q] = v * (&mj.x)[q];
            }
            float s = wq[0] + wq[1] + wq[2] + wq[3];
            s += __shfl_xor(s, 1); s += __shfl_xor(s, 2); s += __shfl_xor(s, 4);
            float inv = mi / (mi * s + 1e-8f);
            bf16x4 wn4;
            #pragma unroll
            for (int q = 0; q < 4; ++q) wn4[q] = (__bf16)(wq[q] * inv);
            *(bf16x4*)&sWN[i0][4 * p0] = wn4;
            sAin[i0][2 * p0]     = (__bf16)(xx0 * ewa0 + xx1 * ewb0 + eb0);
            sAin[i0][2 * p0 + 1] = (__bf16)(xx0 * ewa1 + xx1 * ewb1 + eb1);
        }
        __syncthreads();                                   // B1

        // ===== phase B: transposed gates MFMA + lane-local cell + z1 + w1 stream =====
        {
            bf16x8 bxh[2][2];
            #pragma unroll
            for (int nt = 0; nt < 2; ++nt)
                #pragma unroll
                for (int kt = 0; kt < 2; ++kt)
                    bxh[nt][kt] = *(const bf16x8*)&sAin[nt * 16 + l15][kt * 32 + lg * 8];
            if (t >= 1) {     // z1 += h_{t-1} @ w1[(t-1)*32:]   (sAin h-cols still hold h_{t-1})
                bf16x8 az[2];
                #pragma unroll
                for (int mt = 0; mt < 2; ++mt)
                    az[mt] = *(const bf16x8*)&sAin[mt * 16 + l15][16 + lg * 8];
                #pragma unroll
                for (int mt = 0; mt < 2; ++mt)
                    #pragma unroll
                    for (int ntp = 0; ntp < 2; ++ntp)
                        accZ[mt][ntp] = MFMA(az[mt], Bw1cur[ntp], accZ[mt][ntp]);
            }
            #pragma unroll
            for (int mtl = 0; mtl < 2; ++mtl)
                #pragma unroll
                for (int nt = 0; nt < 2; ++nt) {
                    f32x4 cc = {0.f, 0.f, 0.f, 0.f};
                    cc = MFMA(Ag[mtl][0], bxh[nt][0], cc);
                    cc = MFMA(Ag[mtl][1], bxh[nt][1], cc);
                    // lane holds gates q=0..3 (i,f,g,o) for n=nt*16+l15, h=4*(2w+mtl)+lg
                    float cn = sigf(cc[1]) * cst[mtl][nt] + sigf(cc[0]) * tanhf_(cc[2]);
                    cst[mtl][nt] = cn;
                    sHl[nt * 16 + l15][4 * (2 * w + mtl) + lg] = (__bf16)(sigf(cc[3]) * tanhf_(cn));
                }
            #pragma unroll
            for (int ntp = 0; ntp < 2; ++ntp) {   // stream w1 rows t*32.. (for t+1 / tail)
                int c = (2 * w + ntp) * 16 + l15;
                #pragma unroll
                for (int j = 0; j < 8; ++j)
                    Bw1cur[ntp][j] = (__bf16)w1[(t * 32 + lg * 8 + j) * 128 + c];
            }
        }
        __syncthreads();                                   // B2

        // ===== phase C: ha = hl @ e2a + b -> sPA[:,0:32], sHaT =====
        {
            bf16x8 a = *(const bf16x8*)&sHl[mtw * 16 + l15][lg * 8];
            f32x4 cc = {0.f, 0.f, 0.f, 0.f};
            cc = MFMA(a, Be2a, cc);
            bf16x4 tv;
            #pragma unroll
            for (int q = 0; q < 4; ++q) {
                float v = cc[q] + bEw;
                tv[q] = (__bf16)v;
                sPA[mtw * 16 + 4 * lg + q][cw] = (__bf16)v;
            }
            *(bf16x4*)&sHaT[cw][mtw * 16 + 4 * lg] = tv;
        }
        __syncthreads();                                   // B3

        // ===== phase D: att = wN @ ha -> sPA[:,32:64] =====
        {
            bf16x8 aW = *(const bf16x8*)&sWN [mtw * 16 + l15][lg * 8];
            bf16x8 bT = *(const bf16x8*)&sHaT[cw][lg * 8];
            f32x4 cc = {0.f, 0.f, 0.f, 0.f};
            cc = MFMA(aW, bT, cc);
            #pragma unroll
            for (int q = 0; q < 4; ++q)
                sPA[mtw * 16 + 4 * lg + q][32 + cw] = (__bf16)cc[q];
        }
        __syncthreads();                                   // B4

        // ===== phase E: emb = tanh([ha|att] @ sp + b) =====
        {
            bf16x8 a0 = *(const bf16x8*)&sPA[mtw * 16 + l15][lg * 8];
            bf16x8 a1 = *(const bf16x8*)&sPA[mtw * 16 + l15][32 + lg * 8];
            f32x4 cc = {0.f, 0.f, 0.f, 0.f};
            cc = MFMA(a0, Bsp[0], cc);
            cc = MFMA(a1, Bsp[1], cc);
            #pragma unroll
            for (int q = 0; q < 4; ++q)
                sEmb[mtw * 16 + 4 * lg + q][cw] = (__bf16)tanhf_(cc[q] + bSw);
        }
        __syncthreads();                                   // B5

        // ===== phase F: h_new = emb @ a2e + b -> sAin cols 16-47 =====
        {
            bf16x8 a = *(const bf16x8*)&sEmb[mtw * 16 + l15][lg * 8];
            f32x4 cc = {0.f, 0.f, 0.f, 0.f};
            cc = MFMA(a, Ba2e, cc);
            #pragma unroll
            for (int q = 0; q < 4; ++q)
                sAin[mtw * 16 + 4 * lg + q][16 + cw] = (__bf16)(cc[q] + bAw);
        }
        __syncthreads();                                   // B6
    }

    // ================= tail =================
    // final z1 accumulate (h_19 with w1 rows 608-639)
    {
        bf16x8 az[2];
        #pragma unroll
        for (int mt = 0; mt < 2; ++mt)
            az[mt] = *(const bf16x8*)&sAin[mt * 16 + l15][16 + lg * 8];
        #pragma unroll
        for (int mt = 0; mt < 2; ++mt)
            #pragma unroll
            for (int ntp = 0; ntp < 2; ++ntp)
                accZ[mt][ntp] = MFMA(az[mt], Bw1cur[ntp], accZ[mt][ntp]);
    }
    // z1 = leaky(accZ + b1)
    #pragma unroll
    for (int mt = 0; mt < 2; ++mt)
        #pragma unroll
        for (int ntp = 0; ntp < 2; ++ntp) {
            int c = (2 * w + ntp) * 16 + l15;
            float bias = b1[c];
            #pragma unroll
            for (int q = 0; q < 4; ++q) {
                float v = accZ[mt][ntp][q] + bias;
                v = v > 0.f ? v : 0.2f * v;
                z1bf[mt * 16 + 4 * lg + q][c] = (__bf16)v;
            }
        }
    __syncthreads();

    // z2 = leaky(z1 @ w2 + b2), K=128
    {
        f32x4 c2[2][2] = {};
        #pragma unroll
        for (int kt = 0; kt < 4; ++kt) {
            bf16x8 a[2];
            #pragma unroll
            for (int mt = 0; mt < 2; ++mt)
                a[mt] = *(const bf16x8*)&z1bf[mt * 16 + l15][kt * 32 + lg * 8];
            bf16x8 bb[2];
            #pragma unroll
            for (int ntp = 0; ntp < 2; ++ntp) {
                int c = (2 * w + ntp) * 16 + l15;
                #pragma unroll
                for (int j = 0; j < 8; ++j)
                    bb[ntp][j] = (__bf16)w2[(kt * 32 + lg * 8 + j) * 128 + c];
            }
            #pragma unroll
            for (int mt = 0; mt < 2; ++mt)
                #pragma unroll
                for (int ntp = 0; ntp < 2; ++ntp)
                    c2[mt][ntp] = MFMA(a[mt], bb[ntp], c2[mt][ntp]);
        }
        #pragma unroll
        for (int mt = 0; mt < 2; ++mt)
            #pragma unroll
            for (int ntp = 0; ntp < 2; ++ntp) {
                int c = (2 * w + ntp) * 16 + l15;
                float bias = b2[c];
                #pragma unroll
                for (int q = 0; q < 4; ++q) {
                    float v = c2[mt][ntp][q] + bias;
                    v = v > 0.f ? v : 0.2f * v;
                    z2bf[mt * 16 + 4 * lg + q][c] = (__bf16)v;
                }
            }
    }
    __syncthreads();

    // z3 = sigmoid(z2 @ w3 + b3)
    {
        int n = tid >> 3, kg = tid & 7;
        bf16x8 v0 = *(const bf16x8*)&z2bf[n][kg * 16];
        bf16x8 v1 = *(const bf16x8*)&z2bf[n][kg * 16 + 8];
        float s = 0.f;
        #pragma unroll
        for (int j = 0; j < 8; ++j)
            s += (float)v0[j] * w3[kg * 16 + j] + (float)v1[j] * w3[kg * 16 + 8 + j];
        s += __shfl_xor(s, 1); s += __shfl_xor(s, 2); s += __shfl_xor(s, 4);
        if (kg == 0) out[b * 32 + n] = sigf(s + b3[0]);
    }
}

extern "C" void kernel_launch(void* const* d_in, const int* in_sizes, int n_in,
                              void* d_out, int out_size, void* d_ws, size_t ws_size,
                              hipStream_t stream) {
    (void)in_sizes; (void)n_in; (void)d_ws; (void)ws_size; (void)out_size;
    const float* x     = (const float*)d_in[0];
    const float* dmat  = (const float*)d_in[1];
    const float* bmat  = (const float*)d_in[2];
    const float* hmat  = (const float*)d_in[3];
    const float* mask  = (const float*)d_in[4];
    const float* emb_w = (const float*)d_in[5];
    const float* emb_b = (const float*)d_in[6];
    const float* w_ih  = (const float*)d_in[7];
    const float* w_hh  = (const float*)d_in[8];
    const float* b_ih  = (const float*)d_in[9];
    const float* b_hh  = (const float*)d_in[10];
    const float* e2a_w = (const float*)d_in[11];
    const float* e2a_b = (const float*)d_in[12];
    const float* dom   = (const float*)d_in[13];
    const float* sp_w  = (const float*)d_in[14];
    const float* sp_b  = (const float*)d_in[15];
    const float* a2e_w = (const float*)d_in[16];
    const float* a2e_b = (const float*)d_in[17];
    const float* w1    = (const float*)d_in[18];
    const float* b1    = (const float*)d_in[19];
    const float* w2    = (const float*)d_in[20];
    const float* b2    = (const float*)d_in[21];
    const float* w3    = (const float*)d_in[22];
    const float* b3    = (const float*)d_in[23];
    float* out = (float*)d_out;

    traj_disc_kernel<<<dim3(TD_B), dim3(256), 0, stream>>>(
        x, dmat, bmat, hmat, mask, emb_w, emb_b, w_ih, w_hh, b_ih, b_hh,
        e2a_w, e2a_b, dom, sp_w, sp_b, a2e_w, a2e_b,
        w1, b1, w2, b2, w3, b3, out);
}